// Round 4
// baseline (3368.585 us; speedup 1.0000x reference)
//
#include <hip/hip_runtime.h>
#include <hip/hip_bf16.h>
#include <float.h>

// Problem constants
#define BQ    64      // batch
#define CDIM  640     // channels (K)
#define LQ    441     // query descriptors per image
#define NCLS  32      // support classes
#define MS    2205    // support descriptors per class
#define ITILES 7      // 7*64 = 448 padded rows
#define NJC    9      // 9*256 = 2304 padded cols (blob regions, 256 wide)
#define NMC   3       // gemm works in 3 chunks of 768 cols (12 waves x 64)
#define NKC    10     // 640/64 k-chunks
#define NEG_INF (-3.0e38f)

// A blob: per (b,it) row-major 64 rows x 640 k bf16 = 81920 B (5120 x 16B granules, 80/row)
#define ABYTES 81920
#define ADW    20480
// B blob: per (n,region): [kc][ks][jf][lane] x 16B = 10*2*16*64*16 = 327680 B; per-kc chunk 32768 B
#define BMC    327680
#define BN     (NJC * BMC)   // 2,949,120 B per class

typedef __attribute__((ext_vector_type(8))) short short8;
typedef __attribute__((ext_vector_type(4))) float f32x4;

// sorted top-3 insert: a>=b>=c.  4 VALU ops via v_med3_f32.
__device__ __forceinline__ void ins3(float s, float& a, float& b, float& c) {
  float na = fmaxf(a, s);
  float nb = __builtin_amdgcn_fmed3f(a, b, s);
  c = fmaxf(c, fminf(b, s));
  a = na; b = nb;
}

// ---------------- prep: normalize x1 over C, emit row-major bf16 A tiles [b*7+it][64 i][640 k] ----------------
__global__ __launch_bounds__(1024) void prep_q(const float* __restrict__ x1,
                                               unsigned short* __restrict__ Abf) {
  const int it = blockIdx.x;   // 0..6
  const int b  = blockIdx.y;   // 0..63
  const int t  = threadIdx.x;
  const int il = t & 63, cg = t >> 6;       // cg 0..15
  __shared__ float red[16][64];
  __shared__ float rnq[64];
  __shared__ unsigned short tile[64][66];   // [c][i]

  const int i = it * 64 + il;
  float ss = 0.f;
  if (i < LQ) {
    for (int c = cg; c < CDIM; c += 16) {
      float v = x1[((size_t)b * CDIM + c) * LQ + i];
      ss += v * v;
    }
  }
  red[cg][il] = ss;
  __syncthreads();
  if (t < 64) {
    float s = 0.f;
    #pragma unroll
    for (int g = 0; g < 16; ++g) s += red[g][t];
    rnq[t] = (it * 64 + t < LQ) ? rsqrtf(s) : 0.f;
  }
  __syncthreads();

  unsigned int* blob = (unsigned int*)Abf + (size_t)(b * ITILES + it) * ADW;
  for (int kc = 0; kc < NKC; ++kc) {
    for (int idx = t; idx < 4096; idx += 1024) {
      int cc = idx >> 6, ii = idx & 63;       // consecutive i -> coalesced global read
      int gi = it * 64 + ii;
      float v = 0.f;
      if (gi < LQ) v = x1[((size_t)b * CDIM + kc * 64 + cc) * LQ + gi] * rnq[ii];
      __hip_bfloat16 h = __float2bfloat16(v);
      tile[cc][ii] = *(unsigned short*)&h;
    }
    __syncthreads();
    for (int idx = t; idx < 2048; idx += 1024) {
      int row = idx >> 5, kp = idx & 31;      // consecutive kp -> coalesced global write
      unsigned int lo = tile[kp * 2][row], hi = tile[kp * 2 + 1][row];
      blob[row * 320 + kc * 32 + kp] = lo | (hi << 16);
    }
    __syncthreads();
  }
}

// ---------------- prep: normalize x2 over C, emit MFMA-fragment-order B blob ----------------
// Bbf[n][region] (BMC bytes): granule g = (kc*2+ks)*16*64 + jf*64 + lane, lane = q*16+l15.
// Granule holds B[col = region*256 + jf*16 + l15][k = kc*64 + ks*32 + q*8 .. +7] as 8 bf16.
__global__ __launch_bounds__(1024) void prep_s(const float* __restrict__ x2,
                                               char* __restrict__ Bbf) {
  const int mc = blockIdx.x;   // 0..8
  const int n  = blockIdx.y;   // 0..31
  const int t  = threadIdx.x;
  const int jj = t & 255, cg = t >> 8;      // cg 0..3
  __shared__ float red[4][256];
  __shared__ float rns[256];
  __shared__ unsigned short tile[64][266];   // [c][j], 266 stride -> conflict-lite column reads

  const int j = mc * 256 + jj;
  float ss = 0.f;
  if (j < MS) {
    for (int c = cg; c < CDIM; c += 4) {
      float v = x2[((size_t)n * CDIM + c) * MS + j];
      ss += v * v;
    }
  }
  red[cg][jj] = ss;
  __syncthreads();
  if (t < 256) {
    float s = red[0][t] + red[1][t] + red[2][t] + red[3][t];
    rns[t] = (mc * 256 + t < MS) ? rsqrtf(s) : 0.f;
  }
  __syncthreads();

  char* blob = Bbf + ((size_t)n * NJC + mc) * BMC;
  for (int kc = 0; kc < NKC; ++kc) {
    for (int idx = t; idx < 16384; idx += 1024) {
      int cc = idx >> 8, jc = idx & 255;      // consecutive jc -> coalesced global read
      int gj = mc * 256 + jc;
      float v = 0.f;
      if (gj < MS) v = x2[((size_t)n * CDIM + kc * 64 + cc) * MS + gj] * rns[jc];
      __hip_bfloat16 h = __float2bfloat16(v);
      tile[cc][jc] = *(unsigned short*)&h;
    }
    __syncthreads();
    for (int g = t; g < 2048; g += 1024) {    // consecutive g -> coalesced 16B global writes
      int ks = g >> 10, jf = (g >> 6) & 15, ln = g & 63;
      int qq = ln >> 4, cl = ln & 15;
      int col = jf * 16 + cl, k0 = ks * 32 + qq * 8;
      unsigned int u0 = (unsigned int)tile[k0 + 0][col] | ((unsigned int)tile[k0 + 1][col] << 16);
      unsigned int u1 = (unsigned int)tile[k0 + 2][col] | ((unsigned int)tile[k0 + 3][col] << 16);
      unsigned int u2 = (unsigned int)tile[k0 + 4][col] | ((unsigned int)tile[k0 + 5][col] << 16);
      unsigned int u3 = (unsigned int)tile[k0 + 6][col] | ((unsigned int)tile[k0 + 7][col] << 16);
      int4 w; w.x = u0; w.y = u1; w.z = u2; w.w = u3;
      *(int4*)(blob + (size_t)kc * 32768 + (size_t)g * 16) = w;
    }
    __syncthreads();
  }
}

// ---------------- main: 12-wave block (768 thr), A in LDS, 3x768-col chunks, 3 waves/SIMD ----------------
// 1-D grid 14336. Decode for XCD L2 locality: xcd = bid&7 gets classes n = xcd*4 .. xcd*4+3.
__global__ __launch_bounds__(768, 3) void gemm_topk(const int4* __restrict__ Abf,
                                                    const char* __restrict__ Bbf,
                                                    float* __restrict__ out) {
  const int bid = blockIdx.x;
  const int xcd = bid & 7;
  const int s   = bid >> 3;              // 0..1791
  const int n   = xcd * 4 + s / 448;     // 4 classes per XCD
  const int bx  = s % 448;               // = b*7 + it
  const int b   = bx / 7;
  const int t    = threadIdx.x;          // 0..767
  const int lane = t & 63, wave = t >> 6;  // wave 0..11
  const int l15  = lane & 15, q = lane >> 4;

  __shared__ __align__(16) char smem[ABYTES];   // A tile; reused for merge

  // ---- stage A once, XOR-swizzled: granule (i,g) stored at i*80 + (g ^ (i&7)) ----
  {
    const int4* gA = Abf + (size_t)bx * 5120;
    int4* sA = (int4*)smem;
    for (int g0 = t; g0 < 5120; g0 += 768) {
      int i = g0 / 80;
      int g = g0 - i * 80;
      sA[i * 80 + (g ^ (i & 7))] = gA[g0];
    }
  }
  __syncthreads();

  float t3[16][3];
  #pragma unroll
  for (int r = 0; r < 16; ++r) { t3[r][0] = NEG_INF; t3[r][1] = NEG_INF; t3[r][2] = NEG_INF; }

  // A fragment addressing: byte = (r*16+l15)*1280 + kc*128 + oct*16, oct = (ks*4+q) ^ (l15&7)
  const int swz  = l15 & 7;
  const int oct0 = (q ^ swz) * 16;
  const int oct1 = ((4 + q) ^ swz) * 16;
  const char* Ab = smem + l15 * 1280;
  const int jb = wave * 64 + l15;        // per-lane column base within a 768-col chunk

  // B base: wave w covers blob region 3*mc + (w>>2), sub-tile (w&3) within it.
  const char* Bp = Bbf + (size_t)n * BN + (size_t)(wave >> 2) * BMC
                   + (size_t)(wave & 3) * 4096 + (size_t)lane * 16;

  short8 bcur[2][4], bnxt[2][4];
  #pragma unroll
  for (int ks = 0; ks < 2; ++ks)
    #pragma unroll
    for (int c = 0; c < 4; ++c)
      bcur[ks][c] = *(const short8*)(Bp + ks * 16384 + c * 1024);

  for (int mc = 0; mc < NMC; ++mc) {
    f32x4 acc[4][4];
    #pragma unroll
    for (int r = 0; r < 4; ++r)
      #pragma unroll
      for (int c = 0; c < 4; ++c) acc[r][c] = (f32x4){0.f, 0.f, 0.f, 0.f};

    #pragma unroll 2
    for (int kc = 0; kc < NKC; ++kc) {
      // prefetch: next kc, or next chunk's kc=0 (region +3), or re-read last (in-bounds no-op)
      int poff = (kc < 9) ? (kc + 1) * 32768 : ((mc < NMC - 1) ? 3 * BMC : kc * 32768);
      #pragma unroll
      for (int ks = 0; ks < 2; ++ks)
        #pragma unroll
        for (int c = 0; c < 4; ++c)
          bnxt[ks][c] = *(const short8*)(Bp + poff + ks * 16384 + c * 1024);

      __builtin_amdgcn_s_setprio(1);         // favor the MFMA-phase wave on this SIMD
      #pragma unroll
      for (int ks = 0; ks < 2; ++ks) {
        const int oct = ks ? oct1 : oct0;
        short8 af[4];
        #pragma unroll
        for (int r = 0; r < 4; ++r)
          af[r] = *(const short8*)(Ab + r * 20480 + kc * 128 + oct);
        #pragma unroll
        for (int r = 0; r < 4; ++r)
          #pragma unroll
          for (int c = 0; c < 4; ++c)
            acc[r][c] = __builtin_amdgcn_mfma_f32_16x16x32_bf16(af[r], bcur[ks][c], acc[r][c], 0, 0, 0);
      }
      __builtin_amdgcn_s_setprio(0);

      #pragma unroll
      for (int ks = 0; ks < 2; ++ks)
        #pragma unroll
        for (int c = 0; c < 4; ++c) bcur[ks][c] = bnxt[ks][c];
    }
    Bp += 3 * BMC;                           // advance to next 768-col chunk

    // fold this chunk into running top-3 (uniform mask: single body, no spill)
    #pragma unroll
    for (int c = 0; c < 4; ++c) {
      const bool jv = (mc * 768 + c * 16 + jb) < MS;
      #pragma unroll
      for (int r = 0; r < 4; ++r)
        #pragma unroll
        for (int reg = 0; reg < 4; ++reg) {
          float sv = jv ? acc[r][c][reg] : NEG_INF;
          ins3(sv, t3[r * 4 + reg][0], t3[r * 4 + reg][1], t3[r * 4 + reg][2]);
        }
    }
  }

  // ---- merge per-lane top-3: 3 serialized rounds of the 4-wave 64-slot merge ----
  // mrg row stride 65 slots: 16 rows spread over 16 banks (stride-64 was a 32-way conflict).
  __syncthreads();                          // all waves done reading A; reuse smem
  float* mrg = (float*)smem;                // 64 rows * 65 slots * 3 = 49920 B
  float* aux = (float*)(smem + 49920);      // 64 rows * 12 segs * 3 = 9216 B
  const int g12 = wave >> 2;                // merge group 0..2
  const int w4  = wave & 3;
  for (int g = 0; g < 3; ++g) {
    if (g12 == g) {
      #pragma unroll
      for (int r = 0; r < 4; ++r)
        #pragma unroll
        for (int reg = 0; reg < 4; ++reg) {
          int row = r * 16 + q * 4 + reg;   // C/D layout: row = quad*4 + reg
          int col = w4 * 16 + l15;          // storage slot only
          float* p = &mrg[(row * 65 + col) * 3];
          p[0] = t3[r * 4 + reg][0]; p[1] = t3[r * 4 + reg][1]; p[2] = t3[r * 4 + reg][2];
        }
    }
    __syncthreads();
    if (g12 == g) {
      int tg = t & 255;                     // thread index within the 256-thread group
      int row = tg >> 2, seg = tg & 3;
      float a = NEG_INF, bb = NEG_INF, cc = NEG_INF;
      for (int c0 = seg * 16; c0 < seg * 16 + 16; ++c0) {
        const float* p = &mrg[(row * 65 + c0) * 3];
        ins3(p[0], a, bb, cc); ins3(p[1], a, bb, cc); ins3(p[2], a, bb, cc);
      }
      aux[(row * 12 + g * 4 + seg) * 3 + 0] = a;
      aux[(row * 12 + g * 4 + seg) * 3 + 1] = bb;
      aux[(row * 12 + g * 4 + seg) * 3 + 2] = cc;
    }
    __syncthreads();
  }
  if (t < 64) {
    float a = NEG_INF, bb = NEG_INF, cc = NEG_INF;
    for (int v = 0; v < 36; ++v) ins3(aux[t * 36 + v], a, bb, cc);
    float sum = a + bb + cc;                // padded rows contribute exactly 0
    for (int offr = 32; offr > 0; offr >>= 1) sum += __shfl_down(sum, offr);
    if (t == 0) atomicAdd(&out[b * NCLS + n], sum);
  }
}

extern "C" void kernel_launch(void* const* d_in, const int* in_sizes, int n_in,
                              void* d_out, int out_size, void* d_ws, size_t ws_size,
                              hipStream_t stream) {
  const float* x1 = (const float*)d_in[0];   // [64, 640, 441] fp32
  const float* x2 = (const float*)d_in[1];   // [32, 640, 2205] fp32
  float* out = (float*)d_out;                // [64, 32] fp32

  // workspace: Abf 36,700,160 B | Bbf 94,371,840 B  (total ~131 MB)
  unsigned short* Abf = (unsigned short*)d_ws;
  char* Bbf = (char*)d_ws + (size_t)BQ * ITILES * ABYTES;

  hipMemsetAsync(d_out, 0, BQ * NCLS * sizeof(float), stream);
  prep_q<<<dim3(ITILES, BQ), 1024, 0, stream>>>(x1, Abf);
  prep_s<<<dim3(NJC, NCLS), 1024, 0, stream>>>(x2, Bbf);
  gemm_topk<<<BQ * ITILES * NCLS, 768, 0, stream>>>((const int4*)Abf, Bbf, out);
}